// Round 5
// baseline (134.957 us; speedup 1.0000x reference)
//
#include <hip/hip_runtime.h>

// Reprojection multi-rig model.
// out[i] = intrs[cam]*(p_cam.xy/p_cam.z) + pps[cam] - points_2d[i]
// where p_cam = R(q)*points_3d[pi] + t,
//       q = rel_q (x) ref_q,  t = rel_t + R(rel_q)*ref_t
//
// R5: R4 failed to compile — __builtin_nontemporal_* rejects HIP_vector_type
// structs; use clang ext_vector_type natives instead. Logic identical to R4:
// 4 obs/thread (4x gather MLP), f32 float4 gather tables, nontemporal
// streaming loads/stores.

typedef int   iv4 __attribute__((ext_vector_type(4)));
typedef float fv4 __attribute__((ext_vector_type(4)));

// ---- prep: pad points_3d (stride 3 -> float4) and ref_poses (7 -> 2xfloat4) ----
__global__ __launch_bounds__(256) void prep_kernel(
    const float* __restrict__ pts3, const float* __restrict__ ref,
    float4* __restrict__ pts4, float4* __restrict__ ref8,
    int npts, int ngroups)
{
    int t = blockIdx.x * blockDim.x + threadIdx.x;
    if (t < npts) {
        const float* p = pts3 + 3 * t;
        pts4[t] = make_float4(p[0], p[1], p[2], 0.0f);
    } else {
        int g = t - npts;
        if (g < ngroups) {
            const float* r = ref + 7 * g;
            ref8[2 * g]     = make_float4(r[0], r[1], r[2], r[3]);
            ref8[2 * g + 1] = make_float4(r[4], r[5], r[6], 0.0f);
        }
    }
}

__device__ __forceinline__ float2 compute_obs(
    float px, float py, float pz,
    const float4& r0, const float4& r1,
    const float* __restrict__ s_rel,
    const float* __restrict__ s_intr,
    const float* __restrict__ s_pps,
    int gy, int cam, float2 p2d)
{
    float rtx = r0.x, rty = r0.y, rtz = r0.z;
    float rqx = r0.w, rqy = r1.x, rqz = r1.y, rqw = r1.z;

    const float* lp = s_rel + 7 * gy;
    float ltx = lp[0], lty = lp[1], ltz = lp[2];
    float lqx = lp[3], lqy = lp[4], lqz = lp[5], lqw = lp[6];

    // t = rel_t + quat_rotate(rel_q, ref_t)
    float uvx = lqy * rtz - lqz * rty;
    float uvy = lqz * rtx - lqx * rtz;
    float uvz = lqx * rty - lqy * rtx;
    float uuvx = lqy * uvz - lqz * uvy;
    float uuvy = lqz * uvx - lqx * uvz;
    float uuvz = lqx * uvy - lqy * uvx;
    float tx = ltx + rtx + 2.0f * (lqw * uvx + uuvx);
    float ty = lty + rty + 2.0f * (lqw * uvy + uuvy);
    float tz = ltz + rtz + 2.0f * (lqw * uvz + uuvz);

    // q = quat_mul(rel_q, ref_q)
    float qw = lqw * rqw - (lqx * rqx + lqy * rqy + lqz * rqz);
    float qx = lqw * rqx + rqw * lqx + (lqy * rqz - lqz * rqy);
    float qy = lqw * rqy + rqw * lqy + (lqz * rqx - lqx * rqz);
    float qz = lqw * rqz + rqw * lqz + (lqx * rqy - lqy * rqx);

    // p_cam = quat_rotate(q, p) + t
    float v2x = qy * pz - qz * py;
    float v2y = qz * px - qx * pz;
    float v2z = qx * py - qy * px;
    float w2x = qy * v2z - qz * v2y;
    float w2y = qz * v2x - qx * v2z;
    float w2z = qx * v2y - qy * v2x;
    float pcx = px + 2.0f * (qw * v2x + w2x) + tx;
    float pcy = py + 2.0f * (qw * v2y + w2y) + ty;
    float pcz = pz + 2.0f * (qw * v2z + w2z) + tz;

    float invz = 1.0f / pcz;  // IEEE divide, matches numpy
    float ux = s_intr[2 * cam]     * (pcx * invz) + s_pps[2 * cam];
    float uy = s_intr[2 * cam + 1] * (pcy * invz) + s_pps[2 * cam + 1];
    return make_float2(ux - p2d.x, uy - p2d.y);
}

// ---- hot kernel: 4 observations per thread, f32 gathers ----
__global__ __launch_bounds__(256) void reproj4(
    const float*  __restrict__ points_2d,
    const int*    __restrict__ camera_indices,
    const int*    __restrict__ grouping_indices,
    const int*    __restrict__ point_indices,
    const float*  __restrict__ camera_pps,
    const float*  __restrict__ intrs,
    const float4* __restrict__ pts4,   // [NUM_PTS] {x,y,z,pad}
    const float4* __restrict__ ref8,   // [NUM_GROUPS*2]
    const float*  __restrict__ rel_poses,
    float*        __restrict__ out,
    int n)
{
    __shared__ float s_rel[56];
    __shared__ float s_pps[16];
    __shared__ float s_intr[16];
    int tid = threadIdx.x;
    if (tid < 56) s_rel[tid] = rel_poses[tid];
    if (tid < 16) { s_pps[tid] = camera_pps[tid]; s_intr[tid] = intrs[tid]; }
    __syncthreads();

    int t = blockIdx.x * blockDim.x + tid;
    int base = t * 4;
    if (base >= n) return;

    if (base + 3 < n) {
        // Wide coalesced streaming loads, nontemporal (bypass L2 retention)
        iv4 pi4  = __builtin_nontemporal_load((const iv4*)(point_indices)   + t);
        iv4 cam4 = __builtin_nontemporal_load((const iv4*)(camera_indices)  + t);
        iv4 g01  = __builtin_nontemporal_load((const iv4*)(grouping_indices) + 2 * t);
        iv4 g23  = __builtin_nontemporal_load((const iv4*)(grouping_indices) + 2 * t + 1);
        fv4 p01  = __builtin_nontemporal_load((const fv4*)(points_2d) + 2 * t);
        fv4 p23  = __builtin_nontemporal_load((const fv4*)(points_2d) + 2 * t + 1);

        int pis[4] = {pi4.x, pi4.y, pi4.z, pi4.w};
        int gx[4]  = {g01.x, g01.z, g23.x, g23.z};
        int gy[4]  = {g01.y, g01.w, g23.y, g23.w};
        int cm[4]  = {cam4.x, cam4.y, cam4.z, cam4.w};
        float2 p2d[4] = {make_float2(p01.x, p01.y), make_float2(p01.z, p01.w),
                         make_float2(p23.x, p23.y), make_float2(p23.z, p23.w)};

        // Issue all 12 independent gathers up front (max MLP)
        float4 pt[4], r0[4], r1[4];
#pragma unroll
        for (int k = 0; k < 4; k++) {
            pt[k] = pts4[pis[k]];
            r0[k] = ref8[2 * gx[k]];
            r1[k] = ref8[2 * gx[k] + 1];
        }

        float2 res[4];
#pragma unroll
        for (int k = 0; k < 4; k++) {
            res[k] = compute_obs(pt[k].x, pt[k].y, pt[k].z,
                                 r0[k], r1[k], s_rel, s_intr, s_pps,
                                 gy[k], cm[k], p2d[k]);
        }

        fv4 o0 = {res[0].x, res[0].y, res[1].x, res[1].y};
        fv4 o1 = {res[2].x, res[2].y, res[3].x, res[3].y};
        __builtin_nontemporal_store(o0, (fv4*)(out) + 2 * t);
        __builtin_nontemporal_store(o1, (fv4*)(out) + 2 * t + 1);
    } else {
        // tail (n not multiple of 4)
        for (int i = base; i < n; i++) {
            int gxi = grouping_indices[2 * i], gyi = grouping_indices[2 * i + 1];
            float4 pt = pts4[point_indices[i]];
            float4 r0 = ref8[2 * gxi];
            float4 r1 = ref8[2 * gxi + 1];
            float2 p2d = make_float2(points_2d[2 * i], points_2d[2 * i + 1]);
            float2 r = compute_obs(pt.x, pt.y, pt.z, r0, r1, s_rel, s_intr, s_pps,
                                   gyi, camera_indices[i], p2d);
            out[2 * i] = r.x; out[2 * i + 1] = r.y;
        }
    }
}

// ---- fallback (ws too small): scalar-gather kernel ----
__global__ __launch_bounds__(256) void reproj_kernel(
    const float2* __restrict__ points_2d,
    const int*    __restrict__ camera_indices,
    const int2*   __restrict__ grouping_indices,
    const int*    __restrict__ point_indices,
    const float*  __restrict__ camera_pps,
    const float*  __restrict__ intrs,
    const float*  __restrict__ points_3d,
    const float*  __restrict__ ref_poses,
    const float*  __restrict__ rel_poses,
    float2*       __restrict__ out,
    int n)
{
    __shared__ float s_rel[56];
    __shared__ float s_pps[16];
    __shared__ float s_intr[16];
    int tid = threadIdx.x;
    if (tid < 56) s_rel[tid] = rel_poses[tid];
    if (tid < 16) { s_pps[tid] = camera_pps[tid]; s_intr[tid] = intrs[tid]; }
    __syncthreads();

    int i = blockIdx.x * blockDim.x + tid;
    if (i >= n) return;

    int2 gm = grouping_indices[i];
    const float* rp = ref_poses + 7 * gm.x;
    float4 r0 = make_float4(rp[0], rp[1], rp[2], rp[3]);
    float4 r1 = make_float4(rp[4], rp[5], rp[6], 0.0f);
    const float* pp = points_3d + 3 * point_indices[i];
    out[i] = compute_obs(pp[0], pp[1], pp[2], r0, r1, s_rel, s_intr, s_pps,
                         gm.y, camera_indices[i], points_2d[i]);
}

extern "C" void kernel_launch(void* const* d_in, const int* in_sizes, int n_in,
                              void* d_out, int out_size, void* d_ws, size_t ws_size,
                              hipStream_t stream) {
    const float*  points_2d       = (const float*)d_in[0];
    const int*    camera_indices  = (const int*)d_in[1];
    const int*    grouping        = (const int*)d_in[2];
    const int*    point_indices   = (const int*)d_in[3];
    const float*  camera_pps      = (const float*)d_in[4];
    const float*  intrs           = (const float*)d_in[5];
    const float*  points_3d       = (const float*)d_in[6];
    const float*  ref_poses       = (const float*)d_in[7];
    const float*  rel_poses       = (const float*)d_in[8];

    int n       = in_sizes[1];       // N observations
    int npts    = in_sizes[6] / 3;   // NUM_PTS
    int ngroups = in_sizes[7] / 7;   // NUM_GROUPS

    size_t need = (size_t)npts * 16 + (size_t)ngroups * 32;
    if (ws_size >= need) {
        float4* pts4 = (float4*)d_ws;
        float4* ref8 = (float4*)((char*)d_ws + (size_t)npts * 16);
        int total = npts + ngroups;
        prep_kernel<<<(total + 255) / 256, 256, 0, stream>>>(
            points_3d, ref_poses, pts4, ref8, npts, ngroups);
        int nt = (n + 3) / 4;
        reproj4<<<(nt + 255) / 256, 256, 0, stream>>>(
            points_2d, camera_indices, grouping, point_indices,
            camera_pps, intrs, pts4, ref8, rel_poses, (float*)d_out, n);
    } else {
        reproj_kernel<<<(n + 255) / 256, 256, 0, stream>>>(
            (const float2*)points_2d, camera_indices, (const int2*)grouping,
            point_indices, camera_pps, intrs, points_3d, ref_poses, rel_poses,
            (float2*)d_out, n);
    }
}

// Round 6
// 130.981 us; speedup vs baseline: 1.0304x; 1.0304x over previous
//
#include <hip/hip_runtime.h>

// Reprojection multi-rig model.
// out[i] = intrs[cam]*(p_cam.xy/p_cam.z) + pps[cam] - points_2d[i]
// where p_cam = R(q)*points_3d[pi] + t,
//       q = rel_q (x) ref_q,  t = rel_t + R(rel_q)*ref_t
//
// R6: evidence so far — gather instr count (R2), 4x MLP (R5), and table
// padding/L2-residency (R1 vs R5) ALL have no effect on the ~43us hot
// kernel: it is pinned by the random-64B-line gather service rate.
// Using d_ws costs ~8-10us of timed overhead (268MB poison fill + prep
// launch) and buys nothing. So: single kernel, NO workspace, 4 obs/thread,
// scalar gathers straight from the original tables, nontemporal streams.

typedef int   iv4 __attribute__((ext_vector_type(4)));
typedef float fv4 __attribute__((ext_vector_type(4)));

__device__ __forceinline__ float2 compute_obs(
    float px, float py, float pz,
    const float* __restrict__ r,      // 7 floats: tx ty tz qx qy qz qw
    const float* __restrict__ s_rel,
    const float* __restrict__ s_intr,
    const float* __restrict__ s_pps,
    int gy, int cam, float2 p2d)
{
    float rtx = r[0], rty = r[1], rtz = r[2];
    float rqx = r[3], rqy = r[4], rqz = r[5], rqw = r[6];

    const float* lp = s_rel + 7 * gy;
    float ltx = lp[0], lty = lp[1], ltz = lp[2];
    float lqx = lp[3], lqy = lp[4], lqz = lp[5], lqw = lp[6];

    // t = rel_t + quat_rotate(rel_q, ref_t)
    float uvx = lqy * rtz - lqz * rty;
    float uvy = lqz * rtx - lqx * rtz;
    float uvz = lqx * rty - lqy * rtx;
    float uuvx = lqy * uvz - lqz * uvy;
    float uuvy = lqz * uvx - lqx * uvz;
    float uuvz = lqx * uvy - lqy * uvx;
    float tx = ltx + rtx + 2.0f * (lqw * uvx + uuvx);
    float ty = lty + rty + 2.0f * (lqw * uvy + uuvy);
    float tz = ltz + rtz + 2.0f * (lqw * uvz + uuvz);

    // q = quat_mul(rel_q, ref_q)
    float qw = lqw * rqw - (lqx * rqx + lqy * rqy + lqz * rqz);
    float qx = lqw * rqx + rqw * lqx + (lqy * rqz - lqz * rqy);
    float qy = lqw * rqy + rqw * lqy + (lqz * rqx - lqx * rqz);
    float qz = lqw * rqz + rqw * lqz + (lqx * rqy - lqy * rqx);

    // p_cam = quat_rotate(q, p) + t
    float v2x = qy * pz - qz * py;
    float v2y = qz * px - qx * pz;
    float v2z = qx * py - qy * px;
    float w2x = qy * v2z - qz * v2y;
    float w2y = qz * v2x - qx * v2z;
    float w2z = qx * v2y - qy * v2x;
    float pcx = px + 2.0f * (qw * v2x + w2x) + tx;
    float pcy = py + 2.0f * (qw * v2y + w2y) + ty;
    float pcz = pz + 2.0f * (qw * v2z + w2z) + tz;

    float invz = 1.0f / pcz;  // IEEE divide, matches numpy
    float ux = s_intr[2 * cam]     * (pcx * invz) + s_pps[2 * cam];
    float uy = s_intr[2 * cam + 1] * (pcy * invz) + s_pps[2 * cam + 1];
    return make_float2(ux - p2d.x, uy - p2d.y);
}

// ---- single hot kernel: 4 observations per thread, direct gathers ----
__global__ __launch_bounds__(256) void reproj4(
    const float*  __restrict__ points_2d,
    const int*    __restrict__ camera_indices,
    const int*    __restrict__ grouping_indices,
    const int*    __restrict__ point_indices,
    const float*  __restrict__ camera_pps,
    const float*  __restrict__ intrs,
    const float*  __restrict__ points_3d,   // [NUM_PTS*3]
    const float*  __restrict__ ref_poses,   // [NUM_GROUPS*7]
    const float*  __restrict__ rel_poses,   // [8*7]
    float*        __restrict__ out,
    int n)
{
    __shared__ float s_rel[56];
    __shared__ float s_pps[16];
    __shared__ float s_intr[16];
    int tid = threadIdx.x;
    if (tid < 56) s_rel[tid] = rel_poses[tid];
    if (tid < 16) { s_pps[tid] = camera_pps[tid]; s_intr[tid] = intrs[tid]; }
    __syncthreads();

    int t = blockIdx.x * blockDim.x + tid;
    int base = t * 4;
    if (base >= n) return;

    if (base + 3 < n) {
        // Wide coalesced streaming loads, nontemporal (don't pollute L2)
        iv4 pi4  = __builtin_nontemporal_load((const iv4*)(point_indices)    + t);
        iv4 cam4 = __builtin_nontemporal_load((const iv4*)(camera_indices)   + t);
        iv4 g01  = __builtin_nontemporal_load((const iv4*)(grouping_indices) + 2 * t);
        iv4 g23  = __builtin_nontemporal_load((const iv4*)(grouping_indices) + 2 * t + 1);
        fv4 p01  = __builtin_nontemporal_load((const fv4*)(points_2d) + 2 * t);
        fv4 p23  = __builtin_nontemporal_load((const fv4*)(points_2d) + 2 * t + 1);

        int pis[4] = {pi4.x, pi4.y, pi4.z, pi4.w};
        int gx[4]  = {g01.x, g01.z, g23.x, g23.z};
        int gy[4]  = {g01.y, g01.w, g23.y, g23.w};
        int cm[4]  = {cam4.x, cam4.y, cam4.z, cam4.w};
        float2 p2d[4] = {make_float2(p01.x, p01.y), make_float2(p01.z, p01.w),
                         make_float2(p23.x, p23.y), make_float2(p23.z, p23.w)};

        // Issue all gathers up front; compiler interleaves the loads.
        float pt[4][3], rf[4][7];
#pragma unroll
        for (int k = 0; k < 4; k++) {
            const float* pp = points_3d + 3 * pis[k];
            pt[k][0] = pp[0]; pt[k][1] = pp[1]; pt[k][2] = pp[2];
        }
#pragma unroll
        for (int k = 0; k < 4; k++) {
            const float* rp = ref_poses + 7 * gx[k];
#pragma unroll
            for (int j = 0; j < 7; j++) rf[k][j] = rp[j];
        }

        float2 res[4];
#pragma unroll
        for (int k = 0; k < 4; k++) {
            res[k] = compute_obs(pt[k][0], pt[k][1], pt[k][2],
                                 rf[k], s_rel, s_intr, s_pps,
                                 gy[k], cm[k], p2d[k]);
        }

        fv4 o0 = {res[0].x, res[0].y, res[1].x, res[1].y};
        fv4 o1 = {res[2].x, res[2].y, res[3].x, res[3].y};
        __builtin_nontemporal_store(o0, (fv4*)(out) + 2 * t);
        __builtin_nontemporal_store(o1, (fv4*)(out) + 2 * t + 1);
    } else {
        // tail (n not multiple of 4)
        for (int i = base; i < n; i++) {
            int gxi = grouping_indices[2 * i], gyi = grouping_indices[2 * i + 1];
            const float* pp = points_3d + 3 * point_indices[i];
            const float* rp = ref_poses + 7 * gxi;
            float rf[7];
            for (int j = 0; j < 7; j++) rf[j] = rp[j];
            float2 p2d = make_float2(points_2d[2 * i], points_2d[2 * i + 1]);
            float2 r = compute_obs(pp[0], pp[1], pp[2], rf, s_rel, s_intr, s_pps,
                                   gyi, camera_indices[i], p2d);
            out[2 * i] = r.x; out[2 * i + 1] = r.y;
        }
    }
}

extern "C" void kernel_launch(void* const* d_in, const int* in_sizes, int n_in,
                              void* d_out, int out_size, void* d_ws, size_t ws_size,
                              hipStream_t stream) {
    const float*  points_2d       = (const float*)d_in[0];
    const int*    camera_indices  = (const int*)d_in[1];
    const int*    grouping        = (const int*)d_in[2];
    const int*    point_indices   = (const int*)d_in[3];
    const float*  camera_pps      = (const float*)d_in[4];
    const float*  intrs           = (const float*)d_in[5];
    const float*  points_3d       = (const float*)d_in[6];
    const float*  ref_poses       = (const float*)d_in[7];
    const float*  rel_poses       = (const float*)d_in[8];

    int n  = in_sizes[1];            // N observations
    int nt = (n + 3) / 4;
    reproj4<<<(nt + 255) / 256, 256, 0, stream>>>(
        points_2d, camera_indices, grouping, point_indices,
        camera_pps, intrs, points_3d, ref_poses, rel_poses,
        (float*)d_out, n);
}